// Round 5
// baseline (206.633 us; speedup 1.0000x reference)
//
#include <hip/hip_runtime.h>
#include <stdint.h>

#define NEGC (-1.0e9f)

typedef __attribute__((ext_vector_type(8))) short bf16x8;
typedef __attribute__((ext_vector_type(4))) float f32x4;

// precomputed seq2 forms: hi/lo split bf16 [b][m][d], and transposed bf16 [b][d][m]
__device__ __align__(16) unsigned short g_S2H[32u * 512u * 128u];
__device__ __align__(16) unsigned short g_S2L[32u * 512u * 128u];
__device__ __align__(16) unsigned short g_VT[32u * 128u * 512u];

__device__ __forceinline__ unsigned short f2bf(float f) {
    union { float f; unsigned int u; } v; v.f = f;
    unsigned int r = v.u + 0x7fffu + ((v.u >> 16) & 1u);
    return (unsigned short)(r >> 16);
}
__device__ __forceinline__ float bf2f(unsigned short h) {
    union { float f; unsigned int u; } v; v.u = ((unsigned int)h) << 16;
    return v.f;
}

// ---- prep: seq2 -> bf16 hi/lo split + transposed bf16. 512 blocks (full GPU). ----
__global__ __launch_bounds__(256) void k_prep(const float* __restrict__ seq2) {
    __shared__ unsigned short Lh[32 * 130];
    const int b = blockIdx.x >> 4, c = blockIdx.x & 15, t = threadIdx.x;
    const int m0 = c * 32;

    const float4* src = (const float4*)(seq2 + (size_t)(b * 512 + m0) * 128);
    ushort4* dh = (ushort4*)(g_S2H + (size_t)(b * 512 + m0) * 128);
    ushort4* dl = (ushort4*)(g_S2L + (size_t)(b * 512 + m0) * 128);
#pragma unroll
    for (int p = 0; p < 4; ++p) {
        int idx = p * 256 + t;
        int row = idx >> 5, c4 = idx & 31;
        float4 v = src[idx];
        float vs[4] = {v.x, v.y, v.z, v.w};
        unsigned short hh[4], ll[4];
#pragma unroll
        for (int i = 0; i < 4; ++i) { hh[i] = f2bf(vs[i]); ll[i] = f2bf(vs[i] - bf2f(hh[i])); }
        ushort4 uh{hh[0], hh[1], hh[2], hh[3]};
        ushort4 ul{ll[0], ll[1], ll[2], ll[3]};
        dh[idx] = uh;
        dl[idx] = ul;
#pragma unroll
        for (int i = 0; i < 4; ++i) Lh[row * 130 + c4 * 4 + i] = hh[i];
    }
    __syncthreads();

    const int d = t >> 1, sub = t & 1;
    unsigned short pk[16];
#pragma unroll
    for (int j = 0; j < 16; ++j) pk[j] = Lh[(sub * 16 + j) * 130 + d];
    unsigned short* dst = g_VT + (size_t)(b * 128 + d) * 512 + m0 + sub * 16;
    *(bf16x8*)dst = *(bf16x8*)pk;
    *(bf16x8*)(dst + 8) = *(bf16x8*)(pk + 8);
}

// ---- LDS layout: A2 bf16 [32][512] @0 (32K) | M2 u8 @32768 | REDm @33280 | REDs @33536 ----
#define M2OFF 32768
#define REDOFF 33280
#define LDS_TOTAL 33792

__global__ __launch_bounds__(256, 3) void bidir_main(
    const float* __restrict__ seq1,
    const int* __restrict__ m1, const int* __restrict__ m2,
    float* __restrict__ out0, float* __restrict__ a2out,
    float* __restrict__ a1log)
{
    __shared__ __align__(16) char smem[LDS_TOTAL];

    const int t = threadIdx.x, lane = t & 63, w = t >> 6;
    const int wr = w >> 1, wc = w & 1, q = lane >> 4, fr = lane & 15;
    const int orig = blockIdx.x;
    const int swzb = (orig & 7) * 256 + (orig >> 3);   // XCD-contiguous
    const int b = swzb >> 6, n0 = (swzb & 63) << 5;

    unsigned char* M2u8 = (unsigned char*)(smem + M2OFF);
    float* REDm = (float*)(smem + REDOFF);
    float* REDs = (float*)(smem + REDOFF + 256);

    // stage m2 mask as u8 (consumed after the phase-A barrier)
    if (t < 128) {
        int4 v = ((const int4*)(m2 + b * 512))[t];
        uchar4 u{(unsigned char)v.x, (unsigned char)v.y, (unsigned char)v.z, (unsigned char)v.w};
        *(uchar4*)(M2u8 + t * 4) = u;
    }

    // ---- Q fragments: direct global f32 load + in-register hi/lo split ----
    // lane (q,fr) of wave (wr,wc): A[row = wr*16+fr][k = ks*32 + q*8 .. +8]
    bf16x8 ah[4], al[4];
    {
        const float* qp = seq1 + (size_t)(b * 2048 + n0 + wr * 16 + fr) * 128;
#pragma unroll
        for (int ks = 0; ks < 4; ++ks) {
            float4 v0 = *(const float4*)(qp + ks * 32 + q * 8);
            float4 v1 = *(const float4*)(qp + ks * 32 + q * 8 + 4);
            float vs[8] = {v0.x, v0.y, v0.z, v0.w, v1.x, v1.y, v1.z, v1.w};
            unsigned short hh[8], ll[8];
#pragma unroll
            for (int j = 0; j < 8; ++j) { hh[j] = f2bf(vs[j]); ll[j] = f2bf(vs[j] - bf2f(hh[j])); }
            ah[ks] = *(bf16x8*)hh;
            al[ks] = *(bf16x8*)ll;
        }
    }

    f32x4 acc[8][2];
#pragma unroll
    for (int i = 0; i < 8; ++i) {
        acc[i][0] = (f32x4){0.f, 0.f, 0.f, 0.f};
        acc[i][1] = (f32x4){0.f, 0.f, 0.f, 0.f};
    }

    // ---- phase A: S = seq1 . seq2^T (split bf16, 3 MFMA), B-frags direct from global ----
    // lane (q,fr) B-frag: K[m = wc*256 + mt*32 + s*16 + fr][k = ks*32 + q*8 .. +8]
    {
        const unsigned short* baseH = g_S2H + (size_t)(b * 512 + wc * 256) * 128 + q * 8;
        const unsigned short* baseL = g_S2L + (size_t)(b * 512 + wc * 256) * 128 + q * 8;
#pragma unroll
        for (int mt = 0; mt < 8; ++mt)
#pragma unroll
            for (int s = 0; s < 2; ++s) {
                const unsigned short* rH = baseH + (size_t)(mt * 32 + s * 16 + fr) * 128;
                const unsigned short* rL = baseL + (size_t)(mt * 32 + s * 16 + fr) * 128;
#pragma unroll
                for (int ks = 0; ks < 4; ++ks) {
                    bf16x8 bh = *(const bf16x8*)(rH + ks * 32);
                    bf16x8 bl = *(const bf16x8*)(rL + ks * 32);
                    acc[mt][s] = __builtin_amdgcn_mfma_f32_16x16x32_bf16(al[ks], bh, acc[mt][s], 0, 0, 0);
                    acc[mt][s] = __builtin_amdgcn_mfma_f32_16x16x32_bf16(ah[ks], bl, acc[mt][s], 0, 0, 0);
                    acc[mt][s] = __builtin_amdgcn_mfma_f32_16x16x32_bf16(ah[ks], bh, acc[mt][s], 0, 0, 0);
                }
            }
    }
    __syncthreads();   // barrier #1: M2u8 ready

    // ---- phase B: in-register masked softmax. TRUE m = wc*256 + mt*32 + s*16 + fr ----
#pragma unroll
    for (int mt = 0; mt < 8; ++mt)
#pragma unroll
        for (int s = 0; s < 2; ++s) {
            int m = wc * 256 + mt * 32 + s * 16 + fr;
            bool keep = M2u8[m] != 0;
#pragma unroll
            for (int r = 0; r < 4; ++r)
                acc[mt][s][r] = keep ? acc[mt][s][r] : NEGC;
        }
    float rmax[4];
#pragma unroll
    for (int r = 0; r < 4; ++r) rmax[r] = NEGC;
#pragma unroll
    for (int mt = 0; mt < 8; ++mt)
#pragma unroll
        for (int s = 0; s < 2; ++s)
#pragma unroll
            for (int r = 0; r < 4; ++r) rmax[r] = fmaxf(rmax[r], acc[mt][s][r]);
#pragma unroll
    for (int off = 1; off < 16; off <<= 1)
#pragma unroll
        for (int r = 0; r < 4; ++r) rmax[r] = fmaxf(rmax[r], __shfl_xor(rmax[r], off));
    if (fr == 0) {
#pragma unroll
        for (int r = 0; r < 4; ++r) REDm[wc * 32 + wr * 16 + q * 4 + r] = rmax[r];
    }
    __syncthreads();   // barrier #2
    float RM[4];
#pragma unroll
    for (int r = 0; r < 4; ++r) {
        int rl = wr * 16 + q * 4 + r;
        RM[r] = fmaxf(REDm[rl], REDm[32 + rl]);
    }
    if (t < 32) {  // a1 logits: rmax + (1-m1)*NEG
        float v = fmaxf(REDm[t], REDm[32 + t]);
        float m1v = (float)m1[b * 2048 + n0 + t];
        a1log[b * 2048 + n0 + t] = v + (1.0f - m1v) * NEGC;
    }
    float rs[4] = {0.f, 0.f, 0.f, 0.f};
#pragma unroll
    for (int mt = 0; mt < 8; ++mt)
#pragma unroll
        for (int s = 0; s < 2; ++s)
#pragma unroll
            for (int r = 0; r < 4; ++r) {
                float e = __expf(acc[mt][s][r] - RM[r]);
                acc[mt][s][r] = e;
                rs[r] += e;
            }
#pragma unroll
    for (int off = 1; off < 16; off <<= 1)
#pragma unroll
        for (int r = 0; r < 4; ++r) rs[r] += __shfl_xor(rs[r], off);
    if (fr == 0) {
#pragma unroll
        for (int r = 0; r < 4; ++r) REDs[wc * 32 + wr * 16 + q * 4 + r] = rs[r];
    }
    __syncthreads();   // barrier #3
    float rinv[4];
#pragma unroll
    for (int r = 0; r < 4; ++r) {
        int rl = wr * 16 + q * 4 + r;
        rinv[r] = 1.0f / (REDs[rl] + REDs[32 + rl]);
    }

    // write a2 (global f32, plain stores) + A2 bf16 to LDS for PV, at TRUE m
#pragma unroll
    for (int mt = 0; mt < 8; ++mt)
#pragma unroll
        for (int s = 0; s < 2; ++s) {
            int m = wc * 256 + mt * 32 + s * 16 + fr;
#pragma unroll
            for (int r = 0; r < 4; ++r) {
                int rl = wr * 16 + q * 4 + r;
                float v = acc[mt][s][r] * rinv[r];
                a2out[(size_t)(b * 2048 + n0 + rl) * 512 + m] = v;
                int off = (rl * 1024 + m * 2) ^ ((rl & 7) << 4);
                *(unsigned short*)(smem + off) = f2bf(v);
            }
        }
    __syncthreads();   // barrier #4: A2 ready

    // ---- phase C: out0 = a2 . seq2; A-frag from LDS A2, B-frag direct from g_VT ----
    f32x4 oacc[4];
#pragma unroll
    for (int c = 0; c < 4; ++c) oacc[c] = (f32x4){0.f, 0.f, 0.f, 0.f};

    {
        const int arow = wr * 16 + fr;
        const int asw = (fr & 7) << 4;
        const unsigned short* vbase = g_VT + (size_t)(b * 128) * 512 + q * 8;
#pragma unroll
        for (int kt = 0; kt < 16; ++kt) {
            int aoff = (arow * 1024 + kt * 64 + q * 16) ^ asw;
            bf16x8 pa = *(const bf16x8*)(smem + aoff);
#pragma unroll
            for (int c = 0; c < 4; ++c) {
                int d = wc * 64 + c * 16 + fr;
                bf16x8 bv = *(const bf16x8*)(vbase + (size_t)d * 512 + kt * 32);
                oacc[c] = __builtin_amdgcn_mfma_f32_16x16x32_bf16(pa, bv, oacc[c], 0, 0, 0);
            }
        }
    }

#pragma unroll
    for (int c = 0; c < 4; ++c)
#pragma unroll
        for (int r = 0; r < 4; ++r) {
            int rl = wr * 16 + q * 4 + r;
            int d = wc * 64 + c * 16 + fr;
            out0[(size_t)(b * 2048 + n0 + rl) * 128 + d] = oacc[c][r];
        }
}

// ---- a1 softmax over n (also zero-inits out2 for k_gemv's atomics) ----
__global__ __launch_bounds__(256) void k_a1(float* __restrict__ a1slot,
                                            float* __restrict__ out2) {
    __shared__ float wred[4];
    const int b = blockIdx.x, t = threadIdx.x, lane = t & 63, w = t >> 6;

    if (t < 128) out2[b * 128 + t] = 0.f;

    const float4* Lp = (const float4*)(a1slot + (size_t)b * 2048);
    float4 La = Lp[t * 2], Lb = Lp[t * 2 + 1];
    float l[8] = {La.x, La.y, La.z, La.w, Lb.x, Lb.y, Lb.z, Lb.w};

    float lmax = l[0];
#pragma unroll
    for (int j = 1; j < 8; ++j) lmax = fmaxf(lmax, l[j]);
#pragma unroll
    for (int off = 1; off < 64; off <<= 1) lmax = fmaxf(lmax, __shfl_xor(lmax, off));
    if (lane == 0) wred[w] = lmax;
    __syncthreads();
    float bmax = fmaxf(fmaxf(wred[0], wred[1]), fmaxf(wred[2], wred[3]));

    float e[8]; float s = 0.f;
#pragma unroll
    for (int j = 0; j < 8; ++j) { e[j] = __expf(l[j] - bmax); s += e[j]; }
#pragma unroll
    for (int off = 1; off < 64; off <<= 1) s += __shfl_xor(s, off);
    __syncthreads();
    if (lane == 0) wred[w] = s;
    __syncthreads();
    float inv = 1.0f / (wred[0] + wred[1] + wred[2] + wred[3]);

    float4 o1{e[0] * inv, e[1] * inv, e[2] * inv, e[3] * inv};
    float4 o2v{e[4] * inv, e[5] * inv, e[6] * inv, e[7] * inv};
    ((float4*)(a1slot + (size_t)b * 2048))[t * 2] = o1;
    ((float4*)(a1slot + (size_t)b * 2048))[t * 2 + 1] = o2v;
}

// ---- GEMV: out2 += a1 . seq1 over 256-row chunks (atomic accumulate) ----
__global__ __launch_bounds__(256) void k_gemv(const float* __restrict__ seq1,
                                              const float* __restrict__ a1,
                                              float* __restrict__ out2) {
    __shared__ float a1b[256];
    __shared__ float4 red[8][32];
    const int bid = blockIdx.x, b = bid >> 3, ch = bid & 7, t = threadIdx.x;
    const int n0 = ch * 256;
    if (t < 64) ((float4*)a1b)[t] = ((const float4*)(a1 + (size_t)b * 2048 + n0))[t];
    __syncthreads();
    const int d4 = t & 31, sl = t >> 5;
    float4 acc{0.f, 0.f, 0.f, 0.f};
    const float4* s1 = (const float4*)(seq1 + (size_t)(b * 2048 + n0 + sl * 32) * 128);
#pragma unroll 8
    for (int j = 0; j < 32; ++j) {
        float wv = a1b[sl * 32 + j];
        float4 v = s1[j * 32 + d4];
        acc.x += wv * v.x; acc.y += wv * v.y; acc.z += wv * v.z; acc.w += wv * v.w;
    }
    red[sl][d4] = acc;
    __syncthreads();
    if (t < 32) {
        float4 s0 = red[0][t];
#pragma unroll
        for (int c = 1; c < 8; ++c) {
            float4 v = red[c][t];
            s0.x += v.x; s0.y += v.y; s0.z += v.z; s0.w += v.w;
        }
        float* dst = out2 + b * 128 + t * 4;
        atomicAdd(dst + 0, s0.x);
        atomicAdd(dst + 1, s0.y);
        atomicAdd(dst + 2, s0.z);
        atomicAdd(dst + 3, s0.w);
    }
}

extern "C" void kernel_launch(void* const* d_in, const int* in_sizes, int n_in,
                              void* d_out, int out_size, void* d_ws, size_t ws_size,
                              hipStream_t stream) {
    const float* seq1 = (const float*)d_in[0];
    const float* seq2 = (const float*)d_in[1];
    const int*   m1   = (const int*)d_in[2];
    const int*   m2   = (const int*)d_in[3];
    (void)d_ws; (void)ws_size; (void)n_in; (void)in_sizes;

    float* out  = (float*)d_out;
    float* out0 = out;                 // [32,2048,128]
    float* a2o  = out + 8388608;       // [32,2048,512]
    float* o2   = out + 41943040;      // [32,128]
    float* a1o  = out + 41947136;      // [32,2048] (logits then final a1)

    k_prep<<<dim3(512), dim3(256), 0, stream>>>(seq2);
    bidir_main<<<dim3(2048), dim3(256), 0, stream>>>(seq1, m1, m2, out0, a2o, a1o);
    k_a1<<<dim3(32), dim3(256), 0, stream>>>(a1o, o2);
    k_gemv<<<dim3(256), dim3(256), 0, stream>>>(seq1, a1o, o2);
}

// Round 6
// 100.076 us; speedup vs baseline: 2.0648x; 2.0648x over previous
//
#include <hip/hip_runtime.h>
#include <stdint.h>

#define NEGC (-1.0e9f)

typedef __attribute__((ext_vector_type(8))) short bf16x8;
typedef __attribute__((ext_vector_type(4))) float f32x4;

// precomputed seq2 forms: hi/lo split bf16 [b][m][d], and transposed bf16 [b][d][m]
__device__ __align__(16) unsigned short g_S2H[32u * 512u * 128u];
__device__ __align__(16) unsigned short g_S2L[32u * 512u * 128u];
__device__ __align__(16) unsigned short g_VT[32u * 128u * 512u];

__device__ __forceinline__ unsigned short f2bf(float f) {
    union { float f; unsigned int u; } v; v.f = f;
    unsigned int r = v.u + 0x7fffu + ((v.u >> 16) & 1u);
    return (unsigned short)(r >> 16);
}
__device__ __forceinline__ float bf2f(unsigned short h) {
    union { float f; unsigned int u; } v; v.u = ((unsigned int)h) << 16;
    return v.f;
}

__device__ __forceinline__ void gl_lds16(const void* g, void* l) {
    __builtin_amdgcn_global_load_lds(
        (const __attribute__((address_space(1))) unsigned int*)g,
        (__attribute__((address_space(3))) unsigned int*)l, 16, 0, 0);
}

// ---- prep: seq2 -> bf16 hi/lo split + transposed bf16. 512 blocks (full GPU). ----
__global__ __launch_bounds__(256) void k_prep(const float* __restrict__ seq2) {
    __shared__ unsigned short Lh[32 * 130];
    const int b = blockIdx.x >> 4, c = blockIdx.x & 15, t = threadIdx.x;
    const int m0 = c * 32;

    const float4* src = (const float4*)(seq2 + (size_t)(b * 512 + m0) * 128);
    ushort4* dh = (ushort4*)(g_S2H + (size_t)(b * 512 + m0) * 128);
    ushort4* dl = (ushort4*)(g_S2L + (size_t)(b * 512 + m0) * 128);
#pragma unroll
    for (int p = 0; p < 4; ++p) {
        int idx = p * 256 + t;
        int row = idx >> 5, c4 = idx & 31;
        float4 v = src[idx];
        float vs[4] = {v.x, v.y, v.z, v.w};
        unsigned short hh[4], ll[4];
#pragma unroll
        for (int i = 0; i < 4; ++i) { hh[i] = f2bf(vs[i]); ll[i] = f2bf(vs[i] - bf2f(hh[i])); }
        ushort4 uh{hh[0], hh[1], hh[2], hh[3]};
        ushort4 ul{ll[0], ll[1], ll[2], ll[3]};
        dh[idx] = uh;
        dl[idx] = ul;
#pragma unroll
        for (int i = 0; i < 4; ++i) Lh[row * 130 + c4 * 4 + i] = hh[i];
    }
    __syncthreads();

    const int d = t >> 1, sub = t & 1;
    unsigned short pk[16];
#pragma unroll
    for (int j = 0; j < 16; ++j) pk[j] = Lh[(sub * 16 + j) * 130 + d];
    unsigned short* dst = g_VT + (size_t)(b * 128 + d) * 512 + m0 + sub * 16;
    *(bf16x8*)dst = *(bf16x8*)pk;
    *(bf16x8*)(dst + 8) = *(bf16x8*)(pk + 8);
}

// ---- LDS layout (bytes) ----
// A2 bf16 [32][512] @0 (32K, phase B/C)
// K dbuf @32768: buf*16384 + {KH 8K | KL 8K}   (phase A)
// T dbuf @32768: buf*16384 + T[128][64] 16K    (phase C, overlays K)
// M2 u8 @65536 | REDm @66048 | REDs @66304
#define KBASE 32768
#define TBASE 32768
#define M2OFF 65536
#define REDOFF 66048
#define LDS_TOTAL 66560

__global__ __launch_bounds__(256, 2) void bidir_main(
    const float* __restrict__ seq1,
    const int* __restrict__ m1, const int* __restrict__ m2,
    float* __restrict__ out0, float* __restrict__ a2out,
    float* __restrict__ a1log)
{
    __shared__ __align__(16) char smem[LDS_TOTAL];

    const int t = threadIdx.x, lane = t & 63, w = t >> 6;
    const int wr = w >> 1, wc = w & 1, q = lane >> 4, fr = lane & 15;
    const int orig = blockIdx.x;
    const int swzb = (orig & 7) * 256 + (orig >> 3);   // XCD-contiguous
    const int b = swzb >> 6, n0 = (swzb & 63) << 5;

    unsigned char* M2u8 = (unsigned char*)(smem + M2OFF);
    float* REDm = (float*)(smem + REDOFF);
    float* REDs = (float*)(smem + REDOFF + 256);

    // ---- K-tile stage: tile kt covers m in [kt*16,+16) u [256+kt*16,+16).
    // wave w: (w<2 ? hi : lo) source, half h=w&1; writes local rows h*16+[0,16).
    auto stageK = [&](int buf, int kt) {
        const unsigned short* sb = (w < 2) ? g_S2H : g_S2L;
        const int h = w & 1;
        const char* srcb = (const char*)(sb + (size_t)(b * 512 + h * 256 + kt * 16) * 128);
        char* dstb = smem + KBASE + buf * 16384 + (w >> 1) * 8192 + h * 4096;
#pragma unroll
        for (int i = 0; i < 4; ++i) {
            int r = i * 4 + q;
            int so = r * 256 + ((fr * 16) ^ ((r & 7) << 4));
            gl_lds16(srcb + so, dstb + i * 1024);
        }
    };

    // ---- prologue: issue K(0) stage; overlaps with Q setup below ----
    stageK(0, 0);

    // stage m2 mask as u8
    if (t < 128) {
        int4 v = ((const int4*)(m2 + b * 512))[t];
        uchar4 u{(unsigned char)v.x, (unsigned char)v.y, (unsigned char)v.z, (unsigned char)v.w};
        *(uchar4*)(M2u8 + t * 4) = u;
    }

    // ---- Q fragments: direct global f32 load + in-register hi/lo split ----
    bf16x8 ah[4], al[4];
    {
        const float* qp = seq1 + (size_t)(b * 2048 + n0 + wr * 16 + fr) * 128;
#pragma unroll
        for (int ks = 0; ks < 4; ++ks) {
            float4 v0 = *(const float4*)(qp + ks * 32 + q * 8);
            float4 v1 = *(const float4*)(qp + ks * 32 + q * 8 + 4);
            float vs[8] = {v0.x, v0.y, v0.z, v0.w, v1.x, v1.y, v1.z, v1.w};
            unsigned short hh[8], ll[8];
#pragma unroll
            for (int j = 0; j < 8; ++j) { hh[j] = f2bf(vs[j]); ll[j] = f2bf(vs[j] - bf2f(hh[j])); }
            ah[ks] = *(bf16x8*)hh;
            al[ks] = *(bf16x8*)ll;
        }
    }

    f32x4 acc[8][2];
#pragma unroll
    for (int i = 0; i < 8; ++i) {
        acc[i][0] = (f32x4){0.f, 0.f, 0.f, 0.f};
        acc[i][1] = (f32x4){0.f, 0.f, 0.f, 0.f};
    }

    __syncthreads();   // drains K(0) stage; M2u8 visible

    // ---- phase A: S = seq1 . seq2^T (split bf16, 3 MFMA), 2-phase pipelined ----
    // acc[kt>>1][kt&1] holds TRUE m = wc*256 + kt*16 + fr  (== R4's mt*32+s*16+fr)
#pragma unroll
    for (int kt = 0; kt < 16; ++kt) {
        if (kt < 15) stageK((kt + 1) & 1, kt + 1);   // issue next tile BEFORE compute
        {
            const char* KH = smem + KBASE + (kt & 1) * 16384;
            const char* KL = KH + 8192;
            const int rrow = wc * 16 + fr;
            const int sw = (fr & 7) << 4;
            f32x4 a = acc[kt >> 1][kt & 1];
#pragma unroll
            for (int ks = 0; ks < 4; ++ks) {
                int off = (rrow * 256 + ks * 64 + q * 16) ^ sw;
                bf16x8 bh = *(const bf16x8*)(KH + off);
                bf16x8 bl = *(const bf16x8*)(KL + off);
                a = __builtin_amdgcn_mfma_f32_16x16x32_bf16(al[ks], bh, a, 0, 0, 0);
                a = __builtin_amdgcn_mfma_f32_16x16x32_bf16(ah[ks], bl, a, 0, 0, 0);
                a = __builtin_amdgcn_mfma_f32_16x16x32_bf16(ah[ks], bh, a, 0, 0, 0);
            }
            acc[kt >> 1][kt & 1] = a;
        }
        __syncthreads();   // drains stage(kt+1); guards buffer reuse
    }

    // ---- phase B: in-register masked softmax. TRUE m = wc*256 + mt*32 + s*16 + fr ----
#pragma unroll
    for (int mt = 0; mt < 8; ++mt)
#pragma unroll
        for (int s = 0; s < 2; ++s) {
            int m = wc * 256 + mt * 32 + s * 16 + fr;
            bool keep = M2u8[m] != 0;
#pragma unroll
            for (int r = 0; r < 4; ++r)
                acc[mt][s][r] = keep ? acc[mt][s][r] : NEGC;
        }
    float rmax[4];
#pragma unroll
    for (int r = 0; r < 4; ++r) rmax[r] = NEGC;
#pragma unroll
    for (int mt = 0; mt < 8; ++mt)
#pragma unroll
        for (int s = 0; s < 2; ++s)
#pragma unroll
            for (int r = 0; r < 4; ++r) rmax[r] = fmaxf(rmax[r], acc[mt][s][r]);
#pragma unroll
    for (int off = 1; off < 16; off <<= 1)
#pragma unroll
        for (int r = 0; r < 4; ++r) rmax[r] = fmaxf(rmax[r], __shfl_xor(rmax[r], off));
    if (fr == 0) {
#pragma unroll
        for (int r = 0; r < 4; ++r) REDm[wc * 32 + wr * 16 + q * 4 + r] = rmax[r];
    }
    __syncthreads();
    float RM[4];
#pragma unroll
    for (int r = 0; r < 4; ++r) {
        int rl = wr * 16 + q * 4 + r;
        RM[r] = fmaxf(REDm[rl], REDm[32 + rl]);
    }
    if (t < 32) {  // a1 logits: rmax + (1-m1)*NEG
        float v = fmaxf(REDm[t], REDm[32 + t]);
        float m1v = (float)m1[b * 2048 + n0 + t];
        a1log[b * 2048 + n0 + t] = v + (1.0f - m1v) * NEGC;
    }
    float rs[4] = {0.f, 0.f, 0.f, 0.f};
#pragma unroll
    for (int mt = 0; mt < 8; ++mt)
#pragma unroll
        for (int s = 0; s < 2; ++s)
#pragma unroll
            for (int r = 0; r < 4; ++r) {
                float e = __expf(acc[mt][s][r] - RM[r]);
                acc[mt][s][r] = e;
                rs[r] += e;
            }
#pragma unroll
    for (int off = 1; off < 16; off <<= 1)
#pragma unroll
        for (int r = 0; r < 4; ++r) rs[r] += __shfl_xor(rs[r], off);
    if (fr == 0) {
#pragma unroll
        for (int r = 0; r < 4; ++r) REDs[wc * 32 + wr * 16 + q * 4 + r] = rs[r];
    }
    __syncthreads();
    float rinv[4];
#pragma unroll
    for (int r = 0; r < 4; ++r) {
        int rl = wr * 16 + q * 4 + r;
        rinv[r] = 1.0f / (REDs[rl] + REDs[32 + rl]);
    }

    // ---- T-tile stage for phase C (wave w covers d rows [w*32,+32)) ----
    auto stageT = [&](int buf, int mt) {
        char* dstb = smem + TBASE + buf * 16384 + w * 4096;
#pragma unroll
        for (int i = 0; i < 4; ++i) {
            int d = w * 32 + i * 8 + (lane >> 3);
            int cb = (lane & 7) * 16;
            size_t so = (size_t)(b * 128 + d) * 1024 + mt * 128 + (cb ^ ((d & 7) << 4));
            gl_lds16((const char*)g_VT + so, dstb + i * 1024);
        }
    };
    stageT(0, 0);   // prefetch T(0): K region dead, overlaps a2-write epilogue

    // write a2 (global f32) + A2 bf16 to LDS for PV, at TRUE m
#pragma unroll
    for (int mt = 0; mt < 8; ++mt)
#pragma unroll
        for (int s = 0; s < 2; ++s) {
            int m = wc * 256 + mt * 32 + s * 16 + fr;
#pragma unroll
            for (int r = 0; r < 4; ++r) {
                int rl = wr * 16 + q * 4 + r;
                float v = acc[mt][s][r] * rinv[r];
                a2out[(size_t)(b * 2048 + n0 + rl) * 512 + m] = v;
                int off = (rl * 1024 + m * 2) ^ ((rl & 7) << 4);
                *(unsigned short*)(smem + off) = f2bf(v);
            }
        }
    __syncthreads();   // A2 ready; T(0) drained

    // ---- phase C: out0 = a2 . seq2 (2-phase pipelined T dbuf) ----
    f32x4 oacc[4];
#pragma unroll
    for (int c = 0; c < 4; ++c) oacc[c] = (f32x4){0.f, 0.f, 0.f, 0.f};

#pragma unroll
    for (int mt = 0; mt < 8; ++mt) {
        if (mt < 7) stageT((mt + 1) & 1, mt + 1);   // issue next tile BEFORE compute
        {
            const char* Tb = smem + TBASE + (mt & 1) * 16384;
            const int arow = wr * 16 + fr;
            const int asw = (fr & 7) << 4;
#pragma unroll
            for (int ks = 0; ks < 2; ++ks) {
                int aoff = (arow * 1024 + mt * 128 + ks * 64 + q * 16) ^ asw;
                bf16x8 pa = *(const bf16x8*)(smem + aoff);
#pragma unroll
                for (int c = 0; c < 4; ++c) {
                    int d = wc * 64 + c * 16 + fr;
                    int boff = (d * 128 + ks * 64 + q * 16) ^ ((d & 7) << 4);
                    bf16x8 bv = *(const bf16x8*)(Tb + boff);
                    oacc[c] = __builtin_amdgcn_mfma_f32_16x16x32_bf16(pa, bv, oacc[c], 0, 0, 0);
                }
            }
        }
        if (mt < 7) __syncthreads();
    }

#pragma unroll
    for (int c = 0; c < 4; ++c)
#pragma unroll
        for (int r = 0; r < 4; ++r) {
            int rl = wr * 16 + q * 4 + r;
            int d = wc * 64 + c * 16 + fr;
            out0[(size_t)(b * 2048 + n0 + rl) * 128 + d] = oacc[c][r];
        }
}

// ---- a1 softmax over n (also zero-inits out2 for k_gemv's atomics) ----
__global__ __launch_bounds__(256) void k_a1(float* __restrict__ a1slot,
                                            float* __restrict__ out2) {
    __shared__ float wred[4];
    const int b = blockIdx.x, t = threadIdx.x, lane = t & 63, w = t >> 6;

    if (t < 128) out2[b * 128 + t] = 0.f;

    const float4* Lp = (const float4*)(a1slot + (size_t)b * 2048);
    float4 La = Lp[t * 2], Lb = Lp[t * 2 + 1];
    float l[8] = {La.x, La.y, La.z, La.w, Lb.x, Lb.y, Lb.z, Lb.w};

    float lmax = l[0];
#pragma unroll
    for (int j = 1; j < 8; ++j) lmax = fmaxf(lmax, l[j]);
#pragma unroll
    for (int off = 1; off < 64; off <<= 1) lmax = fmaxf(lmax, __shfl_xor(lmax, off));
    if (lane == 0) wred[w] = lmax;
    __syncthreads();
    float bmax = fmaxf(fmaxf(wred[0], wred[1]), fmaxf(wred[2], wred[3]));

    float e[8]; float s = 0.f;
#pragma unroll
    for (int j = 0; j < 8; ++j) { e[j] = __expf(l[j] - bmax); s += e[j]; }
#pragma unroll
    for (int off = 1; off < 64; off <<= 1) s += __shfl_xor(s, off);
    __syncthreads();
    if (lane == 0) wred[w] = s;
    __syncthreads();
    float inv = 1.0f / (wred[0] + wred[1] + wred[2] + wred[3]);

    float4 o1{e[0] * inv, e[1] * inv, e[2] * inv, e[3] * inv};
    float4 o2v{e[4] * inv, e[5] * inv, e[6] * inv, e[7] * inv};
    ((float4*)(a1slot + (size_t)b * 2048))[t * 2] = o1;
    ((float4*)(a1slot + (size_t)b * 2048))[t * 2 + 1] = o2v;
}

// ---- GEMV: out2 += a1 . seq1 over 256-row chunks (atomic accumulate) ----
__global__ __launch_bounds__(256) void k_gemv(const float* __restrict__ seq1,
                                              const float* __restrict__ a1,
                                              float* __restrict__ out2) {
    __shared__ float a1b[256];
    __shared__ float4 red[8][32];
    const int bid = blockIdx.x, b = bid >> 3, ch = bid & 7, t = threadIdx.x;
    const int n0 = ch * 256;
    if (t < 64) ((float4*)a1b)[t] = ((const float4*)(a1 + (size_t)b * 2048 + n0))[t];
    __syncthreads();
    const int d4 = t & 31, sl = t >> 5;
    float4 acc{0.f, 0.f, 0.f, 0.f};
    const float4* s1 = (const float4*)(seq1 + (size_t)(b * 2048 + n0 + sl * 32) * 128);
#pragma unroll 8
    for (int j = 0; j < 32; ++j) {
        float wv = a1b[sl * 32 + j];
        float4 v = s1[j * 32 + d4];
        acc.x += wv * v.x; acc.y += wv * v.y; acc.z += wv * v.z; acc.w += wv * v.w;
    }
    red[sl][d4] = acc;
    __syncthreads();
    if (t < 32) {
        float4 s0 = red[0][t];
#pragma unroll
        for (int c = 1; c < 8; ++c) {
            float4 v = red[c][t];
            s0.x += v.x; s0.y += v.y; s0.z += v.z; s0.w += v.w;
        }
        float* dst = out2 + b * 128 + t * 4;
        atomicAdd(dst + 0, s0.x);
        atomicAdd(dst + 1, s0.y);
        atomicAdd(dst + 2, s0.z);
        atomicAdd(dst + 3, s0.w);
    }
}

extern "C" void kernel_launch(void* const* d_in, const int* in_sizes, int n_in,
                              void* d_out, int out_size, void* d_ws, size_t ws_size,
                              hipStream_t stream) {
    const float* seq1 = (const float*)d_in[0];
    const float* seq2 = (const float*)d_in[1];
    const int*   m1   = (const int*)d_in[2];
    const int*   m2   = (const int*)d_in[3];
    (void)d_ws; (void)ws_size; (void)n_in; (void)in_sizes;

    float* out  = (float*)d_out;
    float* out0 = out;                 // [32,2048,128]
    float* a2o  = out + 8388608;       // [32,2048,512]
    float* o2   = out + 41943040;      // [32,128]
    float* a1o  = out + 41947136;      // [32,2048] (logits then final a1)

    k_prep<<<dim3(512), dim3(256), 0, stream>>>(seq2);
    bidir_main<<<dim3(2048), dim3(256), 0, stream>>>(seq1, m1, m2, out0, a2o, a1o);
    k_a1<<<dim3(32), dim3(256), 0, stream>>>(a1o, o2);
    k_gemv<<<dim3(256), dim3(256), 0, stream>>>(seq1, a1o, o2);
}

// Round 7
// 95.500 us; speedup vs baseline: 2.1637x; 1.0479x over previous
//
#include <hip/hip_runtime.h>
#include <stdint.h>

#define NEGC (-1.0e9f)

typedef __attribute__((ext_vector_type(8))) short bf16x8;
typedef __attribute__((ext_vector_type(4))) float f32x4;

#define VMCNT(n) asm volatile("s_waitcnt vmcnt(" #n ")" ::: "memory")
#define LGKMCNT0 asm volatile("s_waitcnt lgkmcnt(0)" ::: "memory")
#define SBAR __builtin_amdgcn_s_barrier()
#define SCHED0 __builtin_amdgcn_sched_barrier(0)

// precomputed seq2 forms: hi/lo split bf16 [b][m][d], and transposed bf16 [b][d][m]
__device__ __align__(16) unsigned short g_S2H[32u * 512u * 128u];
__device__ __align__(16) unsigned short g_S2L[32u * 512u * 128u];
__device__ __align__(16) unsigned short g_VT[32u * 128u * 512u];

__device__ __forceinline__ unsigned short f2bf(float f) {
    union { float f; unsigned int u; } v; v.f = f;
    unsigned int r = v.u + 0x7fffu + ((v.u >> 16) & 1u);
    return (unsigned short)(r >> 16);
}
__device__ __forceinline__ float bf2f(unsigned short h) {
    union { float f; unsigned int u; } v; v.u = ((unsigned int)h) << 16;
    return v.f;
}

__device__ __forceinline__ void gl_lds16(const void* g, void* l) {
    __builtin_amdgcn_global_load_lds(
        (const __attribute__((address_space(1))) unsigned int*)g,
        (__attribute__((address_space(3))) unsigned int*)l, 16, 0, 0);
}

// ---- prep: seq2 -> bf16 hi/lo split + transposed bf16. 512 blocks (full GPU). ----
__global__ __launch_bounds__(256) void k_prep(const float* __restrict__ seq2) {
    __shared__ unsigned short Lh[32 * 130];
    const int b = blockIdx.x >> 4, c = blockIdx.x & 15, t = threadIdx.x;
    const int m0 = c * 32;

    const float4* src = (const float4*)(seq2 + (size_t)(b * 512 + m0) * 128);
    ushort4* dh = (ushort4*)(g_S2H + (size_t)(b * 512 + m0) * 128);
    ushort4* dl = (ushort4*)(g_S2L + (size_t)(b * 512 + m0) * 128);
#pragma unroll
    for (int p = 0; p < 4; ++p) {
        int idx = p * 256 + t;
        int row = idx >> 5, c4 = idx & 31;
        float4 v = src[idx];
        float vs[4] = {v.x, v.y, v.z, v.w};
        unsigned short hh[4], ll[4];
#pragma unroll
        for (int i = 0; i < 4; ++i) { hh[i] = f2bf(vs[i]); ll[i] = f2bf(vs[i] - bf2f(hh[i])); }
        ushort4 uh{hh[0], hh[1], hh[2], hh[3]};
        ushort4 ul{ll[0], ll[1], ll[2], ll[3]};
        dh[idx] = uh;
        dl[idx] = ul;
#pragma unroll
        for (int i = 0; i < 4; ++i) Lh[row * 130 + c4 * 4 + i] = hh[i];
    }
    __syncthreads();

    const int d = t >> 1, sub = t & 1;
    unsigned short pk[16];
#pragma unroll
    for (int j = 0; j < 16; ++j) pk[j] = Lh[(sub * 16 + j) * 130 + d];
    unsigned short* dst = g_VT + (size_t)(b * 128 + d) * 512 + m0 + sub * 16;
    *(bf16x8*)dst = *(bf16x8*)pk;
    *(bf16x8*)(dst + 8) = *(bf16x8*)(pk + 8);
}

// ---- LDS layout (bytes) ----
// A2 bf16 [32][512] @0 (32K, phase B/C)
// K dbuf @32768: buf*16384 + {KH 8K | KL 8K}   (phase A)
// T dbuf @32768: buf*16384 + T[128][64] 16K    (phase C, overlays K)
// M2 u8 @65536 | REDm @66048 | REDs @66304
#define KBASE 32768
#define TBASE 32768
#define M2OFF 65536
#define REDOFF 66048
#define LDS_TOTAL 66560

__global__ __launch_bounds__(256, 2) void bidir_main(
    const float* __restrict__ seq1,
    const int* __restrict__ m1, const int* __restrict__ m2,
    float* __restrict__ out0, float* __restrict__ a2out,
    float* __restrict__ a1log)
{
    __shared__ __align__(16) char smem[LDS_TOTAL];

    const int t = threadIdx.x, lane = t & 63, w = t >> 6;
    const int wr = w >> 1, wc = w & 1, q = lane >> 4, fr = lane & 15;
    const int orig = blockIdx.x;
    const int swzb = (orig & 7) * 256 + (orig >> 3);   // XCD-contiguous
    const int b = swzb >> 6, n0 = (swzb & 63) << 5;

    unsigned char* M2u8 = (unsigned char*)(smem + M2OFF);
    float* REDm = (float*)(smem + REDOFF);
    float* REDs = (float*)(smem + REDOFF + 256);

    // K-tile stage: tile kt covers m in [kt*16,+16) u [256+kt*16,+16).
    auto stageK = [&](int buf, int kt) {
        const unsigned short* sb = (w < 2) ? g_S2H : g_S2L;
        const int h = w & 1;
        const char* srcb = (const char*)(sb + (size_t)(b * 512 + h * 256 + kt * 16) * 128);
        char* dstb = smem + KBASE + buf * 16384 + (w >> 1) * 8192 + h * 4096;
#pragma unroll
        for (int i = 0; i < 4; ++i) {
            int r = i * 4 + q;
            int so = r * 256 + ((fr * 16) ^ ((r & 7) << 4));
            gl_lds16(srcb + so, dstb + i * 1024);
        }
    };
    // T-tile stage for phase C (wave w covers d rows [w*32,+32))
    auto stageT = [&](int buf, int mt) {
        char* dstb = smem + TBASE + buf * 16384 + w * 4096;
#pragma unroll
        for (int i = 0; i < 4; ++i) {
            int d = w * 32 + i * 8 + (lane >> 3);
            int cb = (lane & 7) * 16;
            size_t so = (size_t)(b * 128 + d) * 1024 + mt * 128 + (cb ^ ((d & 7) << 4));
            gl_lds16((const char*)g_VT + so, dstb + i * 1024);
        }
    };

    // ---- prologue ----
    stageK(0, 0);                       // K tile 0 in flight

    if (t < 128) {                      // m2 mask as u8 (extra-before in vmcnt FIFO: safe)
        int4 v = ((const int4*)(m2 + b * 512))[t];
        uchar4 u{(unsigned char)v.x, (unsigned char)v.y, (unsigned char)v.z, (unsigned char)v.w};
        *(uchar4*)(M2u8 + t * 4) = u;
    }

    // Q fragments: direct global f32 load + in-register hi/lo split.
    // (split consumes Q => compiler drains Q loads here, before the loop's counted waits)
    bf16x8 ah[4], al[4];
    {
        const float* qp = seq1 + (size_t)(b * 2048 + n0 + wr * 16 + fr) * 128;
#pragma unroll
        for (int ks = 0; ks < 4; ++ks) {
            float4 v0 = *(const float4*)(qp + ks * 32 + q * 8);
            float4 v1 = *(const float4*)(qp + ks * 32 + q * 8 + 4);
            float vs[8] = {v0.x, v0.y, v0.z, v0.w, v1.x, v1.y, v1.z, v1.w};
            unsigned short hh[8], ll[8];
#pragma unroll
            for (int j = 0; j < 8; ++j) { hh[j] = f2bf(vs[j]); ll[j] = f2bf(vs[j] - bf2f(hh[j])); }
            ah[ks] = *(bf16x8*)hh;
            al[ks] = *(bf16x8*)ll;
        }
    }

    stageK(1, 1);                       // K tile 1 in flight

    f32x4 acc[8][2];
#pragma unroll
    for (int i = 0; i < 8; ++i) {
        acc[i][0] = (f32x4){0.f, 0.f, 0.f, 0.f};
        acc[i][1] = (f32x4){0.f, 0.f, 0.f, 0.f};
    }

    // ---- phase A: counted-vmcnt pipeline, 16 tiles, depth-2 prefetch ----
    // acc[kt>>1][kt&1] holds TRUE m = wc*256 + kt*16 + fr
#pragma unroll
    for (int kt = 0; kt < 16; ++kt) {
        if (kt == 15) { VMCNT(0); } else { VMCNT(4); }   // tile kt landed; kt+1 may fly
        SCHED0;
        SBAR;                                            // all waves have tile kt
        SCHED0;
        {
            const char* KH = smem + KBASE + (kt & 1) * 16384;
            const char* KL = KH + 8192;
            const int rrow = wc * 16 + fr;
            const int sw = (fr & 7) << 4;
            f32x4 a = acc[kt >> 1][kt & 1];
            __builtin_amdgcn_s_setprio(1);
#pragma unroll
            for (int ks = 0; ks < 4; ++ks) {
                int off = (rrow * 256 + ks * 64 + q * 16) ^ sw;
                bf16x8 bh = *(const bf16x8*)(KH + off);
                bf16x8 bl = *(const bf16x8*)(KL + off);
                a = __builtin_amdgcn_mfma_f32_16x16x32_bf16(al[ks], bh, a, 0, 0, 0);
                a = __builtin_amdgcn_mfma_f32_16x16x32_bf16(ah[ks], bl, a, 0, 0, 0);
                a = __builtin_amdgcn_mfma_f32_16x16x32_bf16(ah[ks], bh, a, 0, 0, 0);
            }
            __builtin_amdgcn_s_setprio(0);
            acc[kt >> 1][kt & 1] = a;
        }
        LGKMCNT0;                                        // my ds_reads done
        SCHED0;
        SBAR;                                            // all waves done with buf[kt&1]
        SCHED0;
        if (kt < 14) stageK(kt & 1, kt + 2);             // refill just-consumed buffer
    }

    // ---- phase B: in-register masked softmax. TRUE m = wc*256 + mt*32 + s*16 + fr ----
#pragma unroll
    for (int mt = 0; mt < 8; ++mt)
#pragma unroll
        for (int s = 0; s < 2; ++s) {
            int m = wc * 256 + mt * 32 + s * 16 + fr;
            bool keep = M2u8[m] != 0;
#pragma unroll
            for (int r = 0; r < 4; ++r)
                acc[mt][s][r] = keep ? acc[mt][s][r] : NEGC;
        }
    float rmax[4];
#pragma unroll
    for (int r = 0; r < 4; ++r) rmax[r] = NEGC;
#pragma unroll
    for (int mt = 0; mt < 8; ++mt)
#pragma unroll
        for (int s = 0; s < 2; ++s)
#pragma unroll
            for (int r = 0; r < 4; ++r) rmax[r] = fmaxf(rmax[r], acc[mt][s][r]);
#pragma unroll
    for (int off = 1; off < 16; off <<= 1)
#pragma unroll
        for (int r = 0; r < 4; ++r) rmax[r] = fmaxf(rmax[r], __shfl_xor(rmax[r], off));
    if (fr == 0) {
#pragma unroll
        for (int r = 0; r < 4; ++r) REDm[wc * 32 + wr * 16 + q * 4 + r] = rmax[r];
    }
    __syncthreads();
    float RM[4];
#pragma unroll
    for (int r = 0; r < 4; ++r) {
        int rl = wr * 16 + q * 4 + r;
        RM[r] = fmaxf(REDm[rl], REDm[32 + rl]);
    }
    if (t < 32) {  // a1 logits: rmax + (1-m1)*NEG
        float v = fmaxf(REDm[t], REDm[32 + t]);
        float m1v = (float)m1[b * 2048 + n0 + t];
        a1log[b * 2048 + n0 + t] = v + (1.0f - m1v) * NEGC;
    }
    float rs[4] = {0.f, 0.f, 0.f, 0.f};
#pragma unroll
    for (int mt = 0; mt < 8; ++mt)
#pragma unroll
        for (int s = 0; s < 2; ++s)
#pragma unroll
            for (int r = 0; r < 4; ++r) {
                float e = __expf(acc[mt][s][r] - RM[r]);
                acc[mt][s][r] = e;
                rs[r] += e;
            }
#pragma unroll
    for (int off = 1; off < 16; off <<= 1)
#pragma unroll
        for (int r = 0; r < 4; ++r) rs[r] += __shfl_xor(rs[r], off);
    if (fr == 0) {
#pragma unroll
        for (int r = 0; r < 4; ++r) REDs[wc * 32 + wr * 16 + q * 4 + r] = rs[r];
    }
    __syncthreads();
    float rinv[4];
#pragma unroll
    for (int r = 0; r < 4; ++r) {
        int rl = wr * 16 + q * 4 + r;
        rinv[r] = 1.0f / (REDs[rl] + REDs[32 + rl]);
    }

    // issue T(0),T(1) now: they fly under the A2-write epilogue (no drain below)
    stageT(0, 0);
    stageT(1, 1);

    // normalize acc in place + write A2 bf16 to LDS for PV (global a2 store DEFERRED)
#pragma unroll
    for (int mt = 0; mt < 8; ++mt)
#pragma unroll
        for (int s = 0; s < 2; ++s) {
            int m = wc * 256 + mt * 32 + s * 16 + fr;
#pragma unroll
            for (int r = 0; r < 4; ++r) {
                int rl = wr * 16 + q * 4 + r;
                float v = acc[mt][s][r] * rinv[r];
                acc[mt][s][r] = v;
                int off = (rl * 1024 + m * 2) ^ ((rl & 7) << 4);
                *(unsigned short*)(smem + off) = f2bf(v);
            }
        }
    LGKMCNT0;       // my A2 ds_writes committed (vmcnt NOT drained: T0/T1 keep flying)
    SCHED0;
    SBAR;           // all waves' A2 visible
    SCHED0;

    // ---- phase C: out0 = a2 . seq2, counted-vmcnt pipeline, 8 tiles ----
    f32x4 oacc[4];
#pragma unroll
    for (int c = 0; c < 4; ++c) oacc[c] = (f32x4){0.f, 0.f, 0.f, 0.f};

#pragma unroll
    for (int mt = 0; mt < 8; ++mt) {
        if (mt == 7) { VMCNT(0); } else { VMCNT(4); }
        SCHED0;
        SBAR;
        SCHED0;
        {
            const char* Tb = smem + TBASE + (mt & 1) * 16384;
            const int arow = wr * 16 + fr;
            const int asw = (fr & 7) << 4;
            __builtin_amdgcn_s_setprio(1);
#pragma unroll
            for (int ks = 0; ks < 2; ++ks) {
                int aoff = (arow * 1024 + mt * 128 + ks * 64 + q * 16) ^ asw;
                bf16x8 pa = *(const bf16x8*)(smem + aoff);
#pragma unroll
                for (int c = 0; c < 4; ++c) {
                    int d = wc * 64 + c * 16 + fr;
                    int boff = (d * 128 + ks * 64 + q * 16) ^ ((d & 7) << 4);
                    bf16x8 bv = *(const bf16x8*)(Tb + boff);
                    oacc[c] = __builtin_amdgcn_mfma_f32_16x16x32_bf16(pa, bv, oacc[c], 0, 0, 0);
                }
            }
            __builtin_amdgcn_s_setprio(0);
        }
        LGKMCNT0;
        SCHED0;
        SBAR;
        SCHED0;
        if (mt < 6) stageT(mt & 1, mt + 2);
    }

    // ---- epilogue: all global stores (a2 f32 + out0), nothing waits on them ----
#pragma unroll
    for (int mt = 0; mt < 8; ++mt)
#pragma unroll
        for (int s = 0; s < 2; ++s) {
            int m = wc * 256 + mt * 32 + s * 16 + fr;
#pragma unroll
            for (int r = 0; r < 4; ++r) {
                int rl = wr * 16 + q * 4 + r;
                a2out[(size_t)(b * 2048 + n0 + rl) * 512 + m] = acc[mt][s][r];
            }
        }
#pragma unroll
    for (int c = 0; c < 4; ++c)
#pragma unroll
        for (int r = 0; r < 4; ++r) {
            int rl = wr * 16 + q * 4 + r;
            int d = wc * 64 + c * 16 + fr;
            out0[(size_t)(b * 2048 + n0 + rl) * 128 + d] = oacc[c][r];
        }
}

// ---- a1 softmax over n (also zero-inits out2 for k_gemv's atomics) ----
__global__ __launch_bounds__(256) void k_a1(float* __restrict__ a1slot,
                                            float* __restrict__ out2) {
    __shared__ float wred[4];
    const int b = blockIdx.x, t = threadIdx.x, lane = t & 63, w = t >> 6;

    if (t < 128) out2[b * 128 + t] = 0.f;

    const float4* Lp = (const float4*)(a1slot + (size_t)b * 2048);
    float4 La = Lp[t * 2], Lb = Lp[t * 2 + 1];
    float l[8] = {La.x, La.y, La.z, La.w, Lb.x, Lb.y, Lb.z, Lb.w};

    float lmax = l[0];
#pragma unroll
    for (int j = 1; j < 8; ++j) lmax = fmaxf(lmax, l[j]);
#pragma unroll
    for (int off = 1; off < 64; off <<= 1) lmax = fmaxf(lmax, __shfl_xor(lmax, off));
    if (lane == 0) wred[w] = lmax;
    __syncthreads();
    float bmax = fmaxf(fmaxf(wred[0], wred[1]), fmaxf(wred[2], wred[3]));

    float e[8]; float s = 0.f;
#pragma unroll
    for (int j = 0; j < 8; ++j) { e[j] = __expf(l[j] - bmax); s += e[j]; }
#pragma unroll
    for (int off = 1; off < 64; off <<= 1) s += __shfl_xor(s, off);
    __syncthreads();
    if (lane == 0) wred[w] = s;
    __syncthreads();
    float inv = 1.0f / (wred[0] + wred[1] + wred[2] + wred[3]);

    float4 o1{e[0] * inv, e[1] * inv, e[2] * inv, e[3] * inv};
    float4 o2v{e[4] * inv, e[5] * inv, e[6] * inv, e[7] * inv};
    ((float4*)(a1slot + (size_t)b * 2048))[t * 2] = o1;
    ((float4*)(a1slot + (size_t)b * 2048))[t * 2 + 1] = o2v;
}

// ---- GEMV: out2 += a1 . seq1 over 256-row chunks (atomic accumulate) ----
__global__ __launch_bounds__(256) void k_gemv(const float* __restrict__ seq1,
                                              const float* __restrict__ a1,
                                              float* __restrict__ out2) {
    __shared__ float a1b[256];
    __shared__ float4 red[8][32];
    const int bid = blockIdx.x, b = bid >> 3, ch = bid & 7, t = threadIdx.x;
    const int n0 = ch * 256;
    if (t < 64) ((float4*)a1b)[t] = ((const float4*)(a1 + (size_t)b * 2048 + n0))[t];
    __syncthreads();
    const int d4 = t & 31, sl = t >> 5;
    float4 acc{0.f, 0.f, 0.f, 0.f};
    const float4* s1 = (const float4*)(seq1 + (size_t)(b * 2048 + n0 + sl * 32) * 128);
#pragma unroll 8
    for (int j = 0; j < 32; ++j) {
        float wv = a1b[sl * 32 + j];
        float4 v = s1[j * 32 + d4];
        acc.x += wv * v.x; acc.y += wv * v.y; acc.z += wv * v.z; acc.w += wv * v.w;
    }
    red[sl][d4] = acc;
    __syncthreads();
    if (t < 32) {
        float4 s0 = red[0][t];
#pragma unroll
        for (int c = 1; c < 8; ++c) {
            float4 v = red[c][t];
            s0.x += v.x; s0.y += v.y; s0.z += v.z; s0.w += v.w;
        }
        float* dst = out2 + b * 128 + t * 4;
        atomicAdd(dst + 0, s0.x);
        atomicAdd(dst + 1, s0.y);
        atomicAdd(dst + 2, s0.z);
        atomicAdd(dst + 3, s0.w);
    }
}

extern "C" void kernel_launch(void* const* d_in, const int* in_sizes, int n_in,
                              void* d_out, int out_size, void* d_ws, size_t ws_size,
                              hipStream_t stream) {
    const float* seq1 = (const float*)d_in[0];
    const float* seq2 = (const float*)d_in[1];
    const int*   m1   = (const int*)d_in[2];
    const int*   m2   = (const int*)d_in[3];
    (void)d_ws; (void)ws_size; (void)n_in; (void)in_sizes;

    float* out  = (float*)d_out;
    float* out0 = out;                 // [32,2048,128]
    float* a2o  = out + 8388608;       // [32,2048,512]
    float* o2   = out + 41943040;      // [32,128]
    float* a1o  = out + 41947136;      // [32,2048] (logits then final a1)

    k_prep<<<dim3(512), dim3(256), 0, stream>>>(seq2);
    bidir_main<<<dim3(2048), dim3(256), 0, stream>>>(seq1, m1, m2, out0, a2o, a1o);
    k_a1<<<dim3(32), dim3(256), 0, stream>>>(a1o, o2);
    k_gemv<<<dim3(256), dim3(256), 0, stream>>>(seq1, a1o, o2);
}